// Round 1
// baseline (2273.519 us; speedup 1.0000x reference)
//
#include <hip/hip_runtime.h>
#include <math.h>

#define S_LEN 16
#define BSZ   64
#define NN    10000
#define LAT   128
#define DMSG  129
#define DH    257
#define KTAB  2048
#define SCALE 0.08838834764831845f
#define NEG1E9 -1000000000.0f

// ---------------- setup: wv_out = Wv @ W_out, vconst = bv@W_out + b_out ----------------
__global__ void setup1_kernel(const float* __restrict__ Wv, const float* __restrict__ bv,
                              const float* __restrict__ W_out, const float* __restrict__ b_out,
                              float* __restrict__ wv_out, float* __restrict__ vconst) {
    int d = threadIdx.x;
    if (d < DH) {
        float acc = 0.f;
        for (int j = 0; j < LAT; ++j) acc += Wv[d * LAT + j] * W_out[j];
        wv_out[d] = acc;
    }
    if (d == 0) {
        float acc = b_out[0];
        for (int j = 0; j < LAT; ++j) acc += bv[j] * W_out[j];
        *vconst = acc;
    }
}

// ---------------- g table: g(t) = sum_l wv_out[129+l] * cos(t*w_l + b_l) ----------------
__global__ void gtab_kernel(const float* __restrict__ wv_out, const float* __restrict__ tw,
                            const float* __restrict__ tb, float* __restrict__ gtab) {
    __shared__ float s_w[LAT], s_b[LAT], s_wv[LAT];
    int tid = threadIdx.x;
    if (tid < LAT) { s_w[tid] = tw[tid]; s_b[tid] = tb[tid]; s_wv[tid] = wv_out[129 + tid]; }
    __syncthreads();
    int k = blockIdx.x * 256 + tid;
    if (k <= KTAB) {
        float t = (float)k * (1.0f / KTAB);
        float acc = 0.f;
        for (int l = 0; l < LAT; ++l) acc += s_wv[l] * cosf(t * s_w[l] + s_b[l]);
        gtab[k] = acc;
    }
}

// ---------------- mask dtype detector ----------------
__global__ void detect_kernel(const int* __restrict__ mask, int* __restrict__ mode) {
    __shared__ int hasHigh, hasFloat;
    int tid = threadIdx.x;
    if (tid == 0) { hasHigh = 0; hasFloat = 0; }
    __syncthreads();
    for (int i = tid; i < 4096; i += 256) {
        int v = mask[i];
        if ((unsigned)v > 1u) atomicOr(&hasHigh, 1);
        if (v == 0x3F800000) atomicOr(&hasFloat, 1);
    }
    __syncthreads();
    if (tid == 0) *mode = hasFloat ? 2 : (hasHigh ? 1 : 0);
}

// ---------------- GRU: rows 0..63 = src, 64..127 = tgt; reads PRE-update mem ----------------
__global__ void gru_kernel(const float* __restrict__ x, const float* __restrict__ t,
                           const int* __restrict__ source, const int* __restrict__ target,
                           const float* __restrict__ tw, const float* __restrict__ tb,
                           const float* __restrict__ W_ih, const float* __restrict__ W_hh,
                           const float* __restrict__ b_ih, const float* __restrict__ b_hh,
                           const float* __restrict__ mem, float* __restrict__ newh, int s) {
    int r = blockIdx.x;
    int b = r & 63;
    int idx = (r < 64) ? source[s * BSZ + b] : target[s * BSZ + b];
    int tid = threadIdx.x;
    __shared__ float msg[DMSG];
    __shared__ float h[LAT];
    const float* xs = x + ((size_t)(s * BSZ + b)) * NN;
    const float* ts = t + ((size_t)(s * BSZ + b)) * NN;
    if (tid == 0) msg[0] = xs[idx];
    float tv = ts[idx];
    msg[1 + tid] = cosf(tv * tw[tid] + tb[tid]);
    h[tid] = mem[(size_t)idx * LAT + tid];
    __syncthreads();
    int j = tid;
    float gir = b_ih[j], giz = b_ih[128 + j], gin = b_ih[256 + j];
    for (int d = 0; d < DMSG; ++d) {
        float m = msg[d];
        gir += m * W_ih[j * DMSG + d];
        giz += m * W_ih[(128 + j) * DMSG + d];
        gin += m * W_ih[(256 + j) * DMSG + d];
    }
    float ghr = b_hh[j], ghz = b_hh[128 + j], ghn = b_hh[256 + j];
    for (int l = 0; l < LAT; ++l) {
        float hv = h[l];
        ghr += hv * W_hh[j * LAT + l];
        ghz += hv * W_hh[(128 + j) * LAT + l];
        ghn += hv * W_hh[(256 + j) * LAT + l];
    }
    float rr = 1.f / (1.f + expf(-(gir + ghr)));
    float zz = 1.f / (1.f + expf(-(giz + ghz)));
    float nn2 = tanhf(gin + rr * ghn);
    newh[r * LAT + tid] = (1.f - zz) * nn2 + zz * h[tid];
}

// ---------------- ordered scatter: src pass (b ascending) then tgt pass -> numpy last-wins ----------------
__global__ void scatter_kernel(const int* __restrict__ source, const int* __restrict__ target,
                               const float* __restrict__ newh, float* __restrict__ mem, int s) {
    int tid = threadIdx.x;
    for (int b = 0; b < BSZ; ++b) {
        int idx = source[s * BSZ + b];
        mem[(size_t)idx * LAT + tid] = newh[b * LAT + tid];
    }
    for (int b = 0; b < BSZ; ++b) {
        int idx = target[s * BSZ + b];
        mem[(size_t)idx * LAT + tid] = newh[(64 + b) * LAT + tid];
    }
}

// ---------------- q, u = Wk@q, qbk; reads POST-scatter mem[tgt] ----------------
__global__ void qu_kernel(const float* __restrict__ x, const int* __restrict__ target,
                          const float* __restrict__ tb,
                          const float* __restrict__ Wq, const float* __restrict__ bq,
                          const float* __restrict__ Wk, const float* __restrict__ bk,
                          const float* __restrict__ mem, float* __restrict__ u,
                          float* __restrict__ qbk, int s) {
    int b = blockIdx.x, tid = threadIdx.x;
    int tg = target[s * BSZ + b];
    __shared__ float th[DH];
    __shared__ float q[LAT];
    if (tid == 0) th[0] = x[((size_t)(s * BSZ + b)) * NN + tg];
    th[1 + tid] = mem[(size_t)tg * LAT + tid];
    th[129 + tid] = cosf(tb[tid]);
    __syncthreads();
    float acc = bq[tid];
    for (int d = 0; d < DH; ++d) acc += th[d] * Wq[d * LAT + tid];
    q[tid] = acc;
    __syncthreads();
    for (int d = tid; d < DH; d += LAT) {
        float a2 = 0.f;
        for (int j = 0; j < LAT; ++j) a2 += Wk[d * LAT + j] * q[j];
        u[b * DH + d] = a2;
    }
    if (tid == 0) {
        float a3 = 0.f;
        for (int j = 0; j < LAT; ++j) a3 += q[j] * bk[j];
        qbk[b] = a3;
    }
}

// ---------------- per-(b,step) f table: f_b(t) = sum_l u_dt[b,l]*cos(t*w_l+b_l) ----------------
__global__ void ftab_kernel(const float* __restrict__ u, const float* __restrict__ tw,
                            const float* __restrict__ tb, float* __restrict__ ftab) {
    int b = blockIdx.y, tid = threadIdx.x;
    __shared__ float s_u[LAT], s_w[LAT], s_b[LAT];
    if (tid < LAT) { s_u[tid] = u[b * DH + 129 + tid]; s_w[tid] = tw[tid]; s_b[tid] = tb[tid]; }
    __syncthreads();
    int k = blockIdx.x * 256 + tid;
    if (k <= KTAB) {
        float t = (float)k * (1.0f / KTAB);
        float acc = 0.f;
        for (int l = 0; l < LAT; ++l) acc += s_u[l] * cosf(t * s_w[l] + s_b[l]);
        ftab[b * (KTAB + 1) + k] = acc;
    }
}

// ---------------- memdot[b,n] = u_mem[b] . mem[n];  memv[n] = wv_mem . mem[n] ----------------
#define BT 16
#define NT 256
__global__ void memdot_kernel(const float* __restrict__ mem, const float* __restrict__ u,
                              const float* __restrict__ wv_out,
                              float* __restrict__ memdot, float* __restrict__ memv) {
    int tid = threadIdx.x;
    int n0 = blockIdx.x * NT;
    int bb0 = blockIdx.y * BT;
    __shared__ float s_u[BT * LAT];
    __shared__ float s_wv[LAT];
    __shared__ float s_m[NT * 17];
    for (int i = tid; i < BT * LAT; i += 256) {
        int bb = i >> 7, l = i & 127;
        s_u[i] = u[(bb0 + bb) * DH + 1 + l];
    }
    if (tid < LAT) s_wv[tid] = wv_out[1 + tid];
    float acc[BT];
#pragma unroll
    for (int i = 0; i < BT; ++i) acc[i] = 0.f;
    float accv = 0.f;
    for (int l0 = 0; l0 < LAT; l0 += 16) {
        __syncthreads();
        int col = tid & 15, rbase = tid >> 4;
        for (int it = 0; it < 16; ++it) {
            int row = rbase + it * 16;
            int n = n0 + row;
            s_m[row * 17 + col] = (n < NN) ? mem[(size_t)n * LAT + l0 + col] : 0.f;
        }
        __syncthreads();
        const float* mrow = &s_m[tid * 17];
        for (int c = 0; c < 16; ++c) {
            float mv = mrow[c];
            int l = l0 + c;
#pragma unroll
            for (int bb = 0; bb < BT; ++bb) acc[bb] += mv * s_u[bb * LAT + l];
            accv += mv * s_wv[l];
        }
    }
    int n = n0 + tid;
    if (n < NN) {
        for (int bb = 0; bb < BT; ++bb) memdot[(size_t)(bb0 + bb) * NN + n] = acc[bb];
        if (bb0 == 0) memv[n] = accv;
    }
}

// ---------------- fused score + online softmax + logit ----------------
__global__ void attn_kernel(const float* __restrict__ x, const float* __restrict__ t,
                            const void* __restrict__ maskp, const int* __restrict__ modep,
                            const float* __restrict__ u, const float* __restrict__ qbk,
                            const float* __restrict__ ftab, const float* __restrict__ gtab,
                            const float* __restrict__ memdot, const float* __restrict__ memv,
                            const float* __restrict__ wv_out, const float* __restrict__ vconst,
                            float* __restrict__ out, int s) {
    int b = blockIdx.x, tid = threadIdx.x;
    const size_t base = (size_t)(s * BSZ + b) * NN;
    const float* xs = x + base;
    const float* ts = t + base;
    const float* ft = ftab + b * (KTAB + 1);
    const float* md = memdot + (size_t)b * NN;
    int mode = *modep;
    const int* m32 = (const int*)maskp;
    const unsigned char* m8 = (const unsigned char*)maskp;
    const float* mf = (const float*)maskp;
    float u0 = u[b * DH + 0];
    float qb = qbk[b];
    float c0 = wv_out[0];
    float m = -3.0e38f, dd = 0.f, nm = 0.f;
    for (int n = tid; n < NN; n += blockDim.x) {
        float xv = xs[n], tv = ts[n];
        float p = tv * (float)KTAB;
        p = fminf(fmaxf(p, 0.f), (float)KTAB - 0.001f);
        int i = (int)p;
        float fr = p - (float)i;
        float fv = ft[i];   fv += (ft[i + 1] - fv) * fr;
        float gv = gtab[i]; gv += (gtab[i + 1] - gv) * fr;
        float sc = SCALE * (xv * u0 + md[n] + fv + qb);
        bool masked;
        if (mode == 1)      masked = (m8[base + n] == 0);
        else if (mode == 2) masked = (mf[base + n] == 0.f);
        else                masked = (m32[base + n] == 0);
        if (masked) sc = NEG1E9;
        float val = xv * c0 + memv[n] + gv;
        if (sc > m) {
            float a = expf(m - sc);
            dd = dd * a + 1.f;
            nm = nm * a + val;
            m = sc;
        } else {
            float e = expf(sc - m);
            dd += e;
            nm += e * val;
        }
    }
    for (int off = 32; off > 0; off >>= 1) {
        float mo = __shfl_down(m, off, 64);
        float d2 = __shfl_down(dd, off, 64);
        float n2 = __shfl_down(nm, off, 64);
        float M = fmaxf(m, mo);
        float e1 = expf(m - M), e2 = expf(mo - M);
        dd = dd * e1 + d2 * e2;
        nm = nm * e1 + n2 * e2;
        m = M;
    }
    __shared__ float sm[8], sd[8], sn[8];
    int wave = tid >> 6;
    if ((tid & 63) == 0) { sm[wave] = m; sd[wave] = dd; sn[wave] = nm; }
    __syncthreads();
    if (tid == 0) {
        float M = sm[0], D = sd[0], Nm = sn[0];
        int nw = blockDim.x >> 6;
        for (int w2 = 1; w2 < nw; ++w2) {
            float M2 = fmaxf(M, sm[w2]);
            float e1 = expf(M - M2), e2 = expf(sm[w2] - M2);
            D = D * e1 + sd[w2] * e2;
            Nm = Nm * e1 + sn[w2] * e2;
            M = M2;
        }
        out[s * BSZ + b] = Nm / D + vconst[0];
    }
}

extern "C" void kernel_launch(void* const* d_in, const int* in_sizes, int n_in,
                              void* d_out, int out_size, void* d_ws, size_t ws_size,
                              hipStream_t stream) {
    const float* x      = (const float*)d_in[0];
    const float* t      = (const float*)d_in[1];
    const int*   source = (const int*)d_in[2];
    const int*   target = (const int*)d_in[3];
    const void*  maskp  = (const void*)d_in[4];
    const float* tw     = (const float*)d_in[5];
    const float* tb     = (const float*)d_in[6];
    const float* W_ih   = (const float*)d_in[7];
    const float* W_hh   = (const float*)d_in[8];
    const float* b_ih   = (const float*)d_in[9];
    const float* b_hh   = (const float*)d_in[10];
    const float* Wq     = (const float*)d_in[11];
    const float* bq     = (const float*)d_in[12];
    const float* Wk     = (const float*)d_in[13];
    const float* bk     = (const float*)d_in[14];
    const float* Wv     = (const float*)d_in[15];
    const float* bv     = (const float*)d_in[16];
    const float* W_out  = (const float*)d_in[17];
    const float* b_out  = (const float*)d_in[18];
    float* out = (float*)d_out;

    float* w = (float*)d_ws;
    float* mem    = w; w += (size_t)NN * LAT;
    float* newh   = w; w += 128 * LAT;
    float* u      = w; w += BSZ * DH;
    float* qbk    = w; w += BSZ;
    float* ftab   = w; w += BSZ * (KTAB + 1);
    float* gtab   = w; w += (KTAB + 1);
    float* memv   = w; w += NN;
    float* memdot = w; w += (size_t)BSZ * NN;
    float* wv_out = w; w += DH;
    float* vconst = w; w += 1;
    int*   modep  = (int*)w;

    hipMemsetAsync(mem, 0, (size_t)NN * LAT * sizeof(float), stream);
    setup1_kernel<<<1, 320, 0, stream>>>(Wv, bv, W_out, b_out, wv_out, vconst);
    gtab_kernel<<<(KTAB + 256) / 256, 256, 0, stream>>>(wv_out, tw, tb, gtab);
    detect_kernel<<<1, 256, 0, stream>>>((const int*)maskp, modep);

    for (int s = 0; s < S_LEN; ++s) {
        gru_kernel<<<128, 128, 0, stream>>>(x, t, source, target, tw, tb,
                                            W_ih, W_hh, b_ih, b_hh, mem, newh, s);
        scatter_kernel<<<1, 128, 0, stream>>>(source, target, newh, mem, s);
        qu_kernel<<<64, 128, 0, stream>>>(x, target, tb, Wq, bq, Wk, bk, mem, u, qbk, s);
        ftab_kernel<<<dim3((KTAB + 256) / 256, BSZ), 256, 0, stream>>>(u, tw, tb, ftab);
        memdot_kernel<<<dim3((NN + NT - 1) / NT, BSZ / BT), 256, 0, stream>>>(mem, u, wv_out, memdot, memv);
        attn_kernel<<<BSZ, 512, 0, stream>>>(x, t, maskp, modep, u, qbk, ftab, gtab,
                                             memdot, memv, wv_out, vconst, out, s);
    }
}

// Round 2
// 1413.507 us; speedup vs baseline: 1.6084x; 1.6084x over previous
//
#include <hip/hip_runtime.h>
#include <math.h>

#define S_LEN 16
#define BSZ   64
#define NN    10000
#define LAT   128
#define DH    257
#define KTAB  1024
#define CSTRIDE (KTAB + 8)    // costab leading dim
#define FSTRIDE (KTAB + 4)    // ftab leading dim
#define NTILE 64
#define NTILES 157            // ceil(10000/64)
#define SCALE 0.08838834764831845f
#define NEG1E9 -1000000000.0f

// ---------------- setup: wv_out = Wv @ W_out, vconst = bv@W_out + b_out ----------------
__global__ __launch_bounds__(320) void setup1_kernel(
    const float* __restrict__ Wv, const float* __restrict__ bv,
    const float* __restrict__ W_out, const float* __restrict__ b_out,
    float* __restrict__ wv_out, float* __restrict__ vconst) {
    int d = threadIdx.x;
    if (d < DH) {
        float acc = 0.f;
        for (int j = 0; j < LAT; ++j) acc += Wv[d * LAT + j] * W_out[j];
        wv_out[d] = acc;
    }
    if (d == 0) {
        float acc = b_out[0];
        for (int j = 0; j < LAT; ++j) acc += bv[j] * W_out[j];
        *vconst = acc;
    }
}

// ---------------- transposes: W_ihT[d][j], W_hhT[l][j], WkT[j][d] ----------------
__global__ __launch_bounds__(256) void transpose_kernel(
    const float* __restrict__ W_ih, const float* __restrict__ W_hh, const float* __restrict__ Wk,
    float* __restrict__ W_ihT, float* __restrict__ W_hhT, float* __restrict__ WkT) {
    int i = blockIdx.x * 256 + threadIdx.x;
    if (i < 129 * 384) { int d = i / 384, j = i % 384; W_ihT[i] = W_ih[j * 129 + d]; }
    if (i < 128 * 384) { int l = i / 384, j = i % 384; W_hhT[i] = W_hh[j * 128 + l]; }
    if (i < 128 * 260) { int j = i / 260, d = i % 260; if (d < 257) WkT[i] = Wk[d * 128 + j]; }
}

// ---------------- costab[l][p] = cos(p/KTAB * w_l + b_l) ----------------
__global__ __launch_bounds__(256) void costab_kernel(
    const float* __restrict__ tw, const float* __restrict__ tb, float* __restrict__ costab) {
    __shared__ float s_w[LAT], s_b[LAT];
    int tid = threadIdx.x;
    if (tid < LAT) { s_w[tid] = tw[tid]; s_b[tid] = tb[tid]; }
    __syncthreads();
    int p = blockIdx.x * 256 + tid;
    if (p <= KTAB) {
        float t = (float)p * (1.0f / KTAB);
        for (int l = 0; l < LAT; ++l)
            costab[l * CSTRIDE + p] = __cosf(t * s_w[l] + s_b[l]);
    }
}

// ---------------- gtab[p] = sum_l wv_out[129+l] * costab[l][p] ----------------
__global__ __launch_bounds__(256) void gtab2_kernel(
    const float* __restrict__ wv_out, const float* __restrict__ costab, float* __restrict__ gtab) {
    __shared__ float wv_s[LAT];
    int tid = threadIdx.x;
    if (tid < LAT) wv_s[tid] = wv_out[129 + tid];
    __syncthreads();
    int p = blockIdx.x * 256 + tid;
    if (p <= KTAB) {
        float a = 0.f;
        for (int l = 0; l < LAT; ++l) a += wv_s[l] * costab[l * CSTRIDE + p];
        gtab[p] = a;
    }
}

// ---------------- mask dtype detector ----------------
__global__ __launch_bounds__(256) void detect_kernel(const int* __restrict__ mask, int* __restrict__ mode) {
    __shared__ int hasHigh, hasFloat;
    int tid = threadIdx.x;
    if (tid == 0) { hasHigh = 0; hasFloat = 0; }
    __syncthreads();
    for (int i = tid; i < 4096; i += 256) {
        int v = mask[i];
        if ((unsigned)v > 1u) atomicOr(&hasHigh, 1);
        if (v == 0x3F800000) atomicOr(&hasFloat, 1);
    }
    __syncthreads();
    if (tid == 0) *mode = hasFloat ? 2 : (hasHigh ? 1 : 0);
}

// ---------------- combine partials over tiles -> logit ----------------
__device__ __forceinline__ void combine_body(const float* __restrict__ partials,
                                             const float* __restrict__ vconst,
                                             float* __restrict__ out, int ps, int tid) {
    if (tid >= 64) return;
    int b = tid;
    float M = -3.0e38f, D = 0.f, Nm = 0.f;
    const float4* pp = (const float4*)partials + b * NTILES;
    for (int i = 0; i < NTILES; ++i) {
        float4 p = pp[i];
        float M2 = fmaxf(M, p.x);
        float e1 = __expf(M - M2), e2 = __expf(p.x - M2);
        D = D * e1 + p.y * e2;
        Nm = Nm * e1 + p.z * e2;
        M = M2;
    }
    out[ps * BSZ + b] = Nm / D + vconst[0];
}

// ---------------- GRU (blocks 0..127) + combine of previous step (block 128) ----------------
__global__ __launch_bounds__(256) void gru2_kernel(
    const float* __restrict__ x, const float* __restrict__ t,
    const int* __restrict__ source, const int* __restrict__ target,
    const float* __restrict__ tw, const float* __restrict__ tb_,
    const float* __restrict__ W_ihT, const float* __restrict__ W_hhT,
    const float* __restrict__ b_ih, const float* __restrict__ b_hh,
    const float* __restrict__ mem, float* __restrict__ newh,
    const float* __restrict__ partials, const float* __restrict__ vconst,
    float* __restrict__ out, int s) {
    int r = blockIdx.x;
    int tid = threadIdx.x;
    if (r == 128) {                 // combine step s-1 (runs after attn2(s-1))
        if (s > 0) combine_body(partials, vconst, out, s - 1, tid);
        return;
    }
    int b = r & 63;
    int idx = (r < 64) ? source[s * BSZ + b] : target[s * BSZ + b];
    const float* xs = x + (size_t)(s * BSZ + b) * NN;
    const float* ts = t + (size_t)(s * BSZ + b) * NN;
    __shared__ float msg[132], h[128], gi3[384], gh3[384];
    if (tid == 0) msg[0] = xs[idx];
    if (tid < 128) {
        float tv = ts[idx];
        msg[1 + tid] = __cosf(tv * tw[tid] + tb_[tid]);
        h[tid] = mem[(size_t)idx * LAT + tid];
    }
    __syncthreads();
    if (tid < 128) {
        int j = tid;
        float a0 = b_ih[j], a1 = b_ih[128 + j], a2 = b_ih[256 + j];
        for (int d = 0; d < 129; ++d) {
            float m = msg[d];
            const float* col = W_ihT + d * 384;
            a0 += m * col[j]; a1 += m * col[128 + j]; a2 += m * col[256 + j];
        }
        gi3[j] = a0; gi3[128 + j] = a1; gi3[256 + j] = a2;
    } else {
        int j = tid - 128;
        float a0 = b_hh[j], a1 = b_hh[128 + j], a2 = b_hh[256 + j];
        for (int l = 0; l < 128; ++l) {
            float hv = h[l];
            const float* col = W_hhT + l * 384;
            a0 += hv * col[j]; a1 += hv * col[128 + j]; a2 += hv * col[256 + j];
        }
        gh3[j] = a0; gh3[128 + j] = a1; gh3[256 + j] = a2;
    }
    __syncthreads();
    if (tid < 128) {
        int j = tid;
        float rr = 1.f / (1.f + __expf(-(gi3[j] + gh3[j])));
        float zz = 1.f / (1.f + __expf(-(gi3[128 + j] + gh3[128 + j])));
        float nn2 = tanhf(gi3[256 + j] + rr * gh3[256 + j]);
        newh[r * LAT + j] = (1.f - zz) * nn2 + zz * h[j];
    }
}

// ---------------- mid: blocks 0..63 = q/u/qbk/ftab per b; block 64 = ordered scatter ----------------
__global__ __launch_bounds__(256) void mid_kernel(
    const float* __restrict__ x, const int* __restrict__ source, const int* __restrict__ target,
    const float* __restrict__ tb_,
    const float* __restrict__ Wq, const float* __restrict__ bq,
    const float* __restrict__ WkT, const float* __restrict__ bk,
    const float* __restrict__ newh, float* __restrict__ mem,
    float* __restrict__ u0_g, float* __restrict__ qbk_g, float* __restrict__ uT,
    float* __restrict__ ftab, const float* __restrict__ costab, int s) {
    int blk = blockIdx.x;
    int tid = threadIdx.x;
    if (blk == 64) {                 // ordered scatter: src pass then tgt pass (last wins)
        if (tid < 128) {
            for (int b2 = 0; b2 < BSZ; ++b2) {
                int i2 = source[s * BSZ + b2];
                mem[(size_t)i2 * LAT + tid] = newh[b2 * LAT + tid];
            }
            for (int b2 = 0; b2 < BSZ; ++b2) {
                int i2 = target[s * BSZ + b2];
                mem[(size_t)i2 * LAT + tid] = newh[(64 + b2) * LAT + tid];
            }
        }
        return;
    }
    int b = blk;
    __shared__ float th[260], qpart[256], q_s[128], udt_s[128];
    __shared__ int s_last;
    int tg = target[s * BSZ + b];
    if (tid < 64) {
        unsigned long long mball = __ballot(target[s * BSZ + tid] == tg);
        if (tid == 0) s_last = 63 - __builtin_clzll(mball);
    }
    if (tid == 0) th[0] = x[(size_t)(s * BSZ + b) * NN + tg];
    __syncthreads();
    // post-scatter mem[tg] == newh[64 + lastb] (tgt pass always overwrites)
    if (tid < 128) th[1 + tid] = newh[(64 + s_last) * LAT + tid];
    else           th[129 + (tid - 128)] = __cosf(tb_[tid - 128]);
    __syncthreads();
    {   // q = th @ Wq + bq, split the 257-dot across two halves of the block
        int l = tid & 127;
        int half = tid >> 7;
        int d0 = half ? 129 : 0, d1 = half ? 257 : 129;
        float a = 0.f;
        for (int d = d0; d < d1; ++d) a += th[d] * Wq[d * LAT + l];
        qpart[tid] = a;
    }
    __syncthreads();
    if (tid < 128) q_s[tid] = bq[tid] + qpart[tid] + qpart[128 + tid];
    __syncthreads();
    if (tid < 64) {   // qbk = q . bk
        float a = bk[tid] * q_s[tid] + bk[64 + tid] * q_s[64 + tid];
        for (int off = 32; off; off >>= 1) a += __shfl_down(a, off, 64);
        if (tid == 0) qbk_g[b] = a;
    }
    // u[d] = sum_j WkT[j][d] * q[j]   (coalesced over d)
    for (int d = tid; d <= 256; d += 256) {
        float a = 0.f;
        for (int j = 0; j < 128; ++j) a += WkT[j * 260 + d] * q_s[j];
        if (d == 0) u0_g[b] = a;
        else if (d <= 128) uT[(d - 1) * BSZ + b] = a;
        else udt_s[d - 129] = a;
    }
    __syncthreads();
    {   // ftab[b][p] = udt . costab[:,p]  (4 points per thread, float4)
        int p = tid * 4;
        float ax = 0.f, ay = 0.f, az = 0.f, aw = 0.f;
        for (int l = 0; l < 128; ++l) {
            float ul = udt_s[l];
            float4 c = *(const float4*)&costab[l * CSTRIDE + p];
            ax += ul * c.x; ay += ul * c.y; az += ul * c.z; aw += ul * c.w;
        }
        *(float4*)&ftab[b * FSTRIDE + p] = make_float4(ax, ay, az, aw);
        if (tid == 0) {
            float a = 0.f;
            for (int l = 0; l < 128; ++l) a += udt_s[l] * costab[l * CSTRIDE + KTAB];
            ftab[b * FSTRIDE + KTAB] = a;
        }
    }
}

// ---------------- fused scores + mask + online-softmax partials per (b, n-tile) ----------------
__global__ __launch_bounds__(256) void attn2_kernel(
    const float* __restrict__ x, const float* __restrict__ t,
    const void* __restrict__ maskp, const int* __restrict__ modep,
    const float* __restrict__ mem, const float* __restrict__ uT,
    const float* __restrict__ u0_g, const float* __restrict__ qbk_g,
    const float* __restrict__ ftab, const float* __restrict__ gtab,
    const float* __restrict__ wv_out, float* __restrict__ partials, int s) {
    int tile = blockIdx.x;
    int n0 = tile * NTILE;
    int tid = threadIdx.x;
    int tb = tid >> 4, tn = tid & 15;
    __shared__ float memT[64 * 72];   // [l_local][n], stride 72
    __shared__ float uTs[64 * 68];    // [l_local][b], stride 68
    __shared__ float memv_s[64];
    __shared__ float wv_s[128];
    __shared__ float u0_s[64], qbk_s[64];
    int nvalid = NN - n0; if (nvalid > NTILE) nvalid = NTILE;

    if (tid < 128) wv_s[tid] = wv_out[1 + tid];
    if (tid < 64) { u0_s[tid] = u0_g[tid]; qbk_s[tid] = qbk_g[tid]; memv_s[tid] = 0.f; }

    float acc[4][4];
#pragma unroll
    for (int i = 0; i < 4; ++i)
#pragma unroll
        for (int j = 0; j < 4; ++j) acc[i][j] = 0.f;

    for (int l0 = 0; l0 < 128; l0 += 64) {
        __syncthreads();
        {   // stage mem -> memT transposed
            int n_l = tid & 63, lq = (tid >> 6) * 16;
            if (n_l < nvalid) {
                const float* mrow = mem + (size_t)(n0 + n_l) * LAT + l0 + lq;
                float4 a0 = *(const float4*)(mrow + 0);
                float4 a1 = *(const float4*)(mrow + 4);
                float4 a2 = *(const float4*)(mrow + 8);
                float4 a3 = *(const float4*)(mrow + 12);
                memT[(lq + 0) * 72 + n_l] = a0.x; memT[(lq + 1) * 72 + n_l] = a0.y;
                memT[(lq + 2) * 72 + n_l] = a0.z; memT[(lq + 3) * 72 + n_l] = a0.w;
                memT[(lq + 4) * 72 + n_l] = a1.x; memT[(lq + 5) * 72 + n_l] = a1.y;
                memT[(lq + 6) * 72 + n_l] = a1.z; memT[(lq + 7) * 72 + n_l] = a1.w;
                memT[(lq + 8) * 72 + n_l] = a2.x; memT[(lq + 9) * 72 + n_l] = a2.y;
                memT[(lq + 10) * 72 + n_l] = a2.z; memT[(lq + 11) * 72 + n_l] = a2.w;
                memT[(lq + 12) * 72 + n_l] = a3.x; memT[(lq + 13) * 72 + n_l] = a3.y;
                memT[(lq + 14) * 72 + n_l] = a3.z; memT[(lq + 15) * 72 + n_l] = a3.w;
            } else {
                for (int j = 0; j < 16; ++j) memT[(lq + j) * 72 + n_l] = 0.f;
            }
        }
        {   // stage uT chunk -> uTs
            int bq4 = (tid & 15) * 4;
            int ll = (tid >> 4) * 4;
            for (int j = 0; j < 4; ++j) {
                float4 v = *(const float4*)&uT[(l0 + ll + j) * BSZ + bq4];
                *(float4*)&uTs[(ll + j) * 68 + bq4] = v;
            }
        }
        __syncthreads();
        if (tid < 64) {   // memv partial
            float a = memv_s[tid];
            for (int l = 0; l < 64; ++l) a += wv_s[l0 + l] * memT[l * 72 + tid];
            memv_s[tid] = a;
        }
        for (int l = 0; l < 64; ++l) {
            float4 uv = *(const float4*)&uTs[l * 68 + tb * 4];
            float4 mv = *(const float4*)&memT[l * 72 + tn * 4];
            acc[0][0] += uv.x * mv.x; acc[0][1] += uv.x * mv.y; acc[0][2] += uv.x * mv.z; acc[0][3] += uv.x * mv.w;
            acc[1][0] += uv.y * mv.x; acc[1][1] += uv.y * mv.y; acc[1][2] += uv.y * mv.z; acc[1][3] += uv.y * mv.w;
            acc[2][0] += uv.z * mv.x; acc[2][1] += uv.z * mv.y; acc[2][2] += uv.z * mv.z; acc[2][3] += uv.z * mv.w;
            acc[3][0] += uv.w * mv.x; acc[3][1] += uv.w * mv.y; acc[3][2] += uv.w * mv.z; acc[3][3] += uv.w * mv.w;
        }
    }
    __syncthreads();

    const float c0 = wv_out[0];
    int mode = *modep;
    const int* m32 = (const int*)maskp;
    const unsigned char* m8 = (const unsigned char*)maskp;
    const float* mf = (const float*)maskp;

    float pm[4], pd[4], pn[4];
#pragma unroll
    for (int i = 0; i < 4; ++i) { pm[i] = -3.0e38f; pd[i] = 0.f; pn[i] = 0.f; }

    for (int i = 0; i < 4; ++i) {
        int b = tb * 4 + i;
        size_t base = (size_t)(s * BSZ + b) * NN + n0 + tn * 4;
        float xv4[4], tv4[4]; int msk[4], vld[4];
        if (tn * 4 + 3 < nvalid) {
            float4 xx = *(const float4*)(x + base);
            float4 tt = *(const float4*)(t + base);
            xv4[0] = xx.x; xv4[1] = xx.y; xv4[2] = xx.z; xv4[3] = xx.w;
            tv4[0] = tt.x; tv4[1] = tt.y; tv4[2] = tt.z; tv4[3] = tt.w;
            if (mode == 1) {
                unsigned mw = *(const unsigned*)(m8 + base);
                msk[0] = mw & 0xff; msk[1] = (mw >> 8) & 0xff; msk[2] = (mw >> 16) & 0xff; msk[3] = (mw >> 24) & 0xff;
            } else if (mode == 2) {
                float4 mm = *(const float4*)(mf + base);
                msk[0] = (mm.x != 0.f); msk[1] = (mm.y != 0.f); msk[2] = (mm.z != 0.f); msk[3] = (mm.w != 0.f);
            } else {
                int4 mm = *(const int4*)(m32 + base);
                msk[0] = mm.x; msk[1] = mm.y; msk[2] = mm.z; msk[3] = mm.w;
            }
            vld[0] = vld[1] = vld[2] = vld[3] = 1;
        } else {
            for (int j = 0; j < 4; ++j) {
                int n = tn * 4 + j;
                vld[j] = (n < nvalid);
                if (vld[j]) {
                    xv4[j] = x[base + j]; tv4[j] = t[base + j];
                    msk[j] = (mode == 1) ? (int)m8[base + j] : (mode == 2) ? (mf[base + j] != 0.f) : m32[base + j];
                } else { xv4[j] = 0.f; tv4[j] = 0.f; msk[j] = 0; }
            }
        }
        const float* ft = ftab + b * FSTRIDE;
#pragma unroll
        for (int j = 0; j < 4; ++j) {
            if (!vld[j]) continue;
            float xv = xv4[j], tv = tv4[j];
            float p = tv * (float)KTAB;
            p = fminf(fmaxf(p, 0.f), (float)KTAB - 0.001f);
            int ii = (int)p;
            float fr = p - (float)ii;
            float f0 = ft[ii];
            float fv = f0 + (ft[ii + 1] - f0) * fr;
            float g0 = gtab[ii];
            float gv = g0 + (gtab[ii + 1] - g0) * fr;
            float sc = SCALE * (xv * u0_s[b] + acc[i][j] + fv + qbk_s[b]);
            if (msk[j] == 0) sc = NEG1E9;
            float val = xv * c0 + memv_s[tn * 4 + j] + gv;
            if (sc > pm[i]) {
                float a = __expf(pm[i] - sc);
                pd[i] = pd[i] * a + 1.f;
                pn[i] = pn[i] * a + val;
                pm[i] = sc;
            } else {
                float e = __expf(sc - pm[i]);
                pd[i] += e;
                pn[i] += e * val;
            }
        }
    }
    // reduce across the 16 tn-lanes (butterfly within 16-lane groups)
#pragma unroll
    for (int mk2 = 1; mk2 < 16; mk2 <<= 1) {
#pragma unroll
        for (int i = 0; i < 4; ++i) {
            float mo = __shfl_xor(pm[i], mk2);
            float dо = __shfl_xor(pd[i], mk2);
            float no = __shfl_xor(pn[i], mk2);
            float M = fmaxf(pm[i], mo);
            float e1 = __expf(pm[i] - M), e2 = __expf(mo - M);
            pd[i] = pd[i] * e1 + dо * e2;
            pn[i] = pn[i] * e1 + no * e2;
            pm[i] = M;
        }
    }
    if (tn == 0) {
#pragma unroll
        for (int i = 0; i < 4; ++i) {
            int b = tb * 4 + i;
            *(float4*)&partials[(size_t)(b * NTILES + tile) * 4] = make_float4(pm[i], pd[i], pn[i], 0.f);
        }
    }
}

// ---------------- tail combine (step 15) ----------------
__global__ __launch_bounds__(64) void tail_kernel(const float* __restrict__ partials,
                                                  const float* __restrict__ vconst,
                                                  float* __restrict__ out) {
    combine_body(partials, vconst, out, S_LEN - 1, threadIdx.x);
}

extern "C" void kernel_launch(void* const* d_in, const int* in_sizes, int n_in,
                              void* d_out, int out_size, void* d_ws, size_t ws_size,
                              hipStream_t stream) {
    const float* x      = (const float*)d_in[0];
    const float* t      = (const float*)d_in[1];
    const int*   source = (const int*)d_in[2];
    const int*   target = (const int*)d_in[3];
    const void*  maskp  = (const void*)d_in[4];
    const float* tw     = (const float*)d_in[5];
    const float* tb     = (const float*)d_in[6];
    const float* W_ih   = (const float*)d_in[7];
    const float* W_hh   = (const float*)d_in[8];
    const float* b_ih   = (const float*)d_in[9];
    const float* b_hh   = (const float*)d_in[10];
    const float* Wq     = (const float*)d_in[11];
    const float* bq     = (const float*)d_in[12];
    const float* Wk     = (const float*)d_in[13];
    const float* bk     = (const float*)d_in[14];
    const float* Wv     = (const float*)d_in[15];
    const float* bv     = (const float*)d_in[16];
    const float* W_out  = (const float*)d_in[17];
    const float* b_out  = (const float*)d_in[18];
    float* out = (float*)d_out;

    float* w = (float*)d_ws;
    float* mem    = w; w += (size_t)NN * LAT;        // 1,280,000
    float* newh   = w; w += 128 * LAT;               // 16,384
    float* uT     = w; w += LAT * BSZ;               // 8,192
    float* u0_g   = w; w += BSZ;
    float* qbk_g  = w; w += BSZ;
    float* ftab   = w; w += BSZ * FSTRIDE;           // 65,792
    float* gtab   = w; w += FSTRIDE;                 // 1,028
    float* costab = w; w += LAT * CSTRIDE;           // 132,096
    float* partials = w; w += (size_t)BSZ * NTILES * 4; // 40,192
    float* wv_out = w; w += 260;
    float* vconst = w; w += 4;
    float* W_ihT  = w; w += 129 * 384;               // 49,536
    float* W_hhT  = w; w += 128 * 384;               // 49,152
    float* WkT    = w; w += 128 * 260;               // 33,280
    int*   modep  = (int*)w;

    hipMemsetAsync(mem, 0, (size_t)NN * LAT * sizeof(float), stream);
    setup1_kernel<<<1, 320, 0, stream>>>(Wv, bv, W_out, b_out, wv_out, vconst);
    transpose_kernel<<<(129 * 384 + 255) / 256, 256, 0, stream>>>(W_ih, W_hh, Wk, W_ihT, W_hhT, WkT);
    costab_kernel<<<(KTAB + 256) / 256, 256, 0, stream>>>(tw, tb, costab);
    gtab2_kernel<<<(KTAB + 256) / 256, 256, 0, stream>>>(wv_out, costab, gtab);
    detect_kernel<<<1, 256, 0, stream>>>((const int*)maskp, modep);

    for (int s = 0; s < S_LEN; ++s) {
        gru2_kernel<<<129, 256, 0, stream>>>(x, t, source, target, tw, tb,
                                             W_ihT, W_hhT, b_ih, b_hh, mem, newh,
                                             partials, vconst, out, s);
        mid_kernel<<<65, 256, 0, stream>>>(x, source, target, tb, Wq, bq, WkT, bk,
                                           newh, mem, u0_g, qbk_g, uT, ftab, costab, s);
        attn2_kernel<<<NTILES, 256, 0, stream>>>(x, t, maskp, modep, mem, uT, u0_g, qbk_g,
                                                 ftab, gtab, wv_out, partials, s);
    }
    tail_kernel<<<1, 64, 0, stream>>>(partials, vconst, out);
}